// Round 9
// baseline (3049.182 us; speedup 1.0000x reference)
//
#include <hip/hip_runtime.h>
#include <hip/hip_bf16.h>
#include <float.h>
#include <math.h>

#define BATCH 16
#define NPTS  4096
#define CIN   64
#define MCENT 1024
#define KNB   32
#define OUT_X (BATCH * MCENT * 128)

// ---- exact (non-contracted) f32 ops: bitwise-match numpy's separate roundings ----
__device__ __forceinline__ float f_sub(float a, float b){ float r; asm("v_sub_f32 %0, %1, %2" : "=v"(r) : "v"(a), "v"(b)); return r; }
__device__ __forceinline__ float f_mul(float a, float b){ float r; asm("v_mul_f32 %0, %1, %2" : "=v"(r) : "v"(a), "v"(b)); return r; }
__device__ __forceinline__ float f_add(float a, float b){ float r; asm("v_add_f32 %0, %1, %2" : "=v"(r) : "v"(a), "v"(b)); return r; }

__device__ __forceinline__ float dist2_exact(float px, float py, float pz,
                                             float lx, float ly, float lz) {
    float dx = f_sub(px, lx), dy = f_sub(py, ly), dz = f_sub(pz, lz);
    return f_add(f_add(f_mul(dx, dx), f_mul(dy, dy)), f_mul(dz, dz));
}

// DPP max step (bound_ctrl=false, full masks: OOB lanes fall back to old = x, fmax(x,x)=x safe)
template <int CTRL>
__device__ __forceinline__ float dpp_max(float x) {
    int xi = __float_as_int(x);
    int yi = __builtin_amdgcn_update_dpp(xi, xi, CTRL, 0xF, 0xF, false);
    return fmaxf(x, __int_as_float(yi));
}
// max over each 32-lane half (no xor32)
__device__ __forceinline__ float half_max_f32(float v) {
    v = dpp_max<0xB1>(v);   // quad_perm xor1
    v = dpp_max<0x4E>(v);   // quad_perm xor2
    v = dpp_max<0x141>(v);  // row_half_mirror (4-group merge)
    v = dpp_max<0x140>(v);  // row_mirror (8-group merge)
    int s = __builtin_amdgcn_ds_swizzle(__float_as_int(v), 0x401F); // xor16 (within 32)
    return fmaxf(v, __int_as_float(s));
}
// full wave max
__device__ __forceinline__ float wave_max_f32(float v) {
    v = half_max_f32(v);
    float a = v, b = v;
    asm("v_permlane32_swap_b32 %0, %1" : "+v"(a), "+v"(b));  // xor32 (VALU)
    return fmaxf(a, b);
}

// ================= K1: farthest point sampling =================
// one block/batch; 512 threads; thread owns 8 contiguous points in registers.
// Per iteration: in-wave argmax (DPP + ballot/shfl), lane0 writes packed u64 key,
// ONE barrier, everyone scans the 8 keys (broadcast reads) -> winner. No atomics,
// no post-barrier dependent slot write. Keys double-buffered for race freedom.
__global__ __launch_bounds__(512, 1) void fps_kernel(
    const float* __restrict__ pos, float* __restrict__ cpos)
{
    __shared__ __align__(16) float4 sp[NPTS];                 // 64KB xyz+pad
    __shared__ __align__(16) unsigned long long swkey[2][8];
    __shared__ int widxarr[MCENT];

    const int b = blockIdx.x;
    const int t = threadIdx.x;
    const int lane = t & 63, wv = t >> 6;
    const float* pb = pos + (size_t)b * NPTS * 3;

    float px[8], py[8], pz[8], mind[8];
    {
        const float4* src = (const float4*)(pb + t * 24);
        float v[24];
#pragma unroll
        for (int q = 0; q < 6; ++q) {
            float4 f = src[q];
            v[q*4+0]=f.x; v[q*4+1]=f.y; v[q*4+2]=f.z; v[q*4+3]=f.w;
        }
#pragma unroll
        for (int jj = 0; jj < 8; ++jj) {
            int n = t * 8 + jj;
            px[jj]=v[jj*3+0]; py[jj]=v[jj*3+1]; pz[jj]=v[jj*3+2];
            sp[n] = make_float4(px[jj], py[jj], pz[jj], 0.f);
            mind[jj] = 1e10f;
        }
    }
    if (t == 0) widxarr[0] = 0;
    __syncthreads();

    int w = 0;
    for (int i = 1; i < MCENT; ++i) {
        float4 L = sp[w];                       // broadcast b128
#pragma unroll
        for (int jj = 0; jj < 8; ++jj) {
            float d = dist2_exact(px[jj], py[jj], pz[jj], L.x, L.y, L.z);
            mind[jj] = fminf(mind[jj], d);
        }
        float tmax = fmaxf(fmaxf(fmaxf(mind[0],mind[1]), fmaxf(mind[2],mind[3])),
                           fmaxf(fmaxf(mind[4],mind[5]), fmaxf(mind[6],mind[7])));
        float wmax = wave_max_f32(tmax);
        int cand = 0;
#pragma unroll
        for (int jj = 7; jj >= 0; --jj)
            if (mind[jj] == wmax) cand = t * 8 + jj;      // smallest matching j wins
        // smallest point index in wave = smallest matching lane (lanes own ascending ranges)
        unsigned long long msk = __ballot(tmax == wmax);  // nonzero by construction
        int first = __ffsll(msk) - 1;
        int candw = __shfl(cand, first);
        if (lane == 0)
            swkey[i & 1][wv] = ((unsigned long long)__float_as_uint(wmax) << 32)
                             | (unsigned)(NPTS - 1 - candw);
        __syncthreads();                        // the only barrier per iteration
        unsigned long long best = swkey[i & 1][0];
#pragma unroll
        for (int q = 1; q < 8; ++q) {
            unsigned long long o = swkey[i & 1][q];
            best = o > best ? o : best;         // larger dist wins; tie -> smaller index
        }
        w = (NPTS - 1) - (int)(unsigned)(best & 0xFFFFFFFFull);
        if (t == 0) widxarr[i] = w;
    }
    __syncthreads();
#pragma unroll
    for (int e = 0; e < 2; ++e) {
        int c = t + e * 512;
        float4 P = sp[widxarr[c]];
        float* cp = cpos + ((size_t)b * MCENT + c) * 3;
        cp[0] = P.x; cp[1] = P.y; cp[2] = P.z;
    }
}

// ================= K2: ball query (first K in index order within radius) =================
__global__ __launch_bounds__(256) void ballq_kernel(
    const float* __restrict__ pos, const float* __restrict__ cpos,
    int* __restrict__ nidx)
{
    const int wid  = blockIdx.x * 4 + (threadIdx.x >> 6);
    const int lane = threadIdx.x & 63;
    const int b    = wid >> 10;
    const float* pb = pos + (size_t)b * NPTS * 3;
    const float cx = cpos[wid * 3 + 0];
    const float cy = cpos[wid * 3 + 1];
    const float cz = cpos[wid * 3 + 2];
    const float R2 = (float)(0.2 * 0.2);
    int* outp = nidx + (size_t)wid * KNB;

    int cnt = 0;
    for (int j0 = 0; j0 < NPTS; j0 += 64) {
        int j = j0 + lane;
        float x = pb[j * 3 + 0], y = pb[j * 3 + 1], z = pb[j * 3 + 2];
        float d = dist2_exact(x, y, z, cx, cy, cz);
        bool valid = (d <= R2);
        unsigned long long msk = __ballot(valid);
        if (valid) {
            int rank = cnt + __popcll(msk & ((1ull << lane) - 1ull));
            if (rank < KNB) outp[rank] = j;
        }
        cnt += __popcll(msk);
        if (cnt >= KNB) break;
    }
    int nv = cnt < KNB ? cnt : KNB;
    if (lane >= nv && lane < KNB) outp[lane] = -1;
}

// ================= K3: gather + shared MLP + DPP max-pool =================
// 256 threads = 8 centroids x 32 neighbor-rows; one row per thread.
// Activation row in REGISTERS (full static unroll); weights via SGPR-broadcast
// s_load (pure-smem lgkmcnt -> pipelineable). LDS only for BN constants (2KB).
// Pool: the 32 rows of a centroid are one 32-lane half-wave -> DPP max reduce.
__global__ __launch_bounds__(256, 1) void mlp_kernel(
    const float* __restrict__ x, const float* __restrict__ pos,
    const float* __restrict__ W1, const float* __restrict__ g1, const float* __restrict__ b1,
    const float* __restrict__ rm1, const float* __restrict__ rv1,
    const float* __restrict__ W2, const float* __restrict__ g2, const float* __restrict__ b2,
    const float* __restrict__ rm2, const float* __restrict__ rv2,
    const float* __restrict__ W3, const float* __restrict__ g3, const float* __restrict__ b3,
    const float* __restrict__ rm3, const float* __restrict__ rv3,
    const float* __restrict__ cpos, const int* __restrict__ nidx,
    float* __restrict__ out)
{
    __shared__ __align__(16) float sscale[256];
    __shared__ __align__(16) float sbias[256];

    const int t   = threadIdx.x;
    const int g   = t >> 5;               // centroid within block
    const int k   = t & 31;               // neighbor slot (= lane&31)
    const int cid0 = blockIdx.x * 8;
    const int cid  = cid0 + g;
    const int b    = cid >> 10;

    // fused BN(eval) constants: y = h*scale + bias
    {
        float gg, bb, rm, rv;
        if (t < 64)       { gg = g1[t];     bb = b1[t];     rm = rm1[t];     rv = rv1[t]; }
        else if (t < 128) { int c = t - 64;  gg = g2[c]; bb = b2[c]; rm = rm2[c]; rv = rv2[c]; }
        else              { int c = t - 128; gg = g3[c]; bb = b3[c]; rm = rm3[c]; rv = rv3[c]; }
        float s = gg / sqrtf(rv + 1e-5f);
        sscale[t] = s;
        sbias[t]  = bb - rm * s;
    }

    const int j = nidx[(size_t)cid * KNB + k];
    const bool valid = (j >= 0);
    float h[67];
    if (valid) {
        const float4* xr = (const float4*)(x + ((size_t)b * NPTS + j) * CIN);
#pragma unroll
        for (int q = 0; q < 16; ++q) {
            float4 v = xr[q];
            h[q*4+0]=v.x; h[q*4+1]=v.y; h[q*4+2]=v.z; h[q*4+3]=v.w;
        }
        const float* pr = pos + ((size_t)b * NPTS + j) * 3;
        h[64] = f_sub(pr[0], cpos[cid * 3 + 0]);
        h[65] = f_sub(pr[1], cpos[cid * 3 + 1]);
        h[66] = f_sub(pr[2], cpos[cid * 3 + 2]);
    } else {
#pragma unroll
        for (int q = 0; q < 67; ++q) h[q] = 0.f;
    }
    __syncthreads();   // sscale/sbias ready

    float acc[64];
    // ---- layer 1: 67 -> 64 ----
#pragma unroll
    for (int c = 0; c < 64; ++c) acc[c] = 0.f;
#pragma unroll
    for (int kk = 0; kk < 67; ++kk) {
        const float hv = h[kk];
        const float* wr = W1 + kk * 64;     // wave-uniform -> s_load
#pragma unroll
        for (int c = 0; c < 64; ++c) acc[c] = fmaf(hv, wr[c], acc[c]);
    }
#pragma unroll
    for (int c4 = 0; c4 < 16; ++c4) {
        float4 sc = *(const float4*)&sscale[c4 * 4];
        float4 sb = *(const float4*)&sbias[c4 * 4];
        h[c4*4+0] = fmaxf(fmaf(acc[c4*4+0], sc.x, sb.x), 0.f);
        h[c4*4+1] = fmaxf(fmaf(acc[c4*4+1], sc.y, sb.y), 0.f);
        h[c4*4+2] = fmaxf(fmaf(acc[c4*4+2], sc.z, sb.z), 0.f);
        h[c4*4+3] = fmaxf(fmaf(acc[c4*4+3], sc.w, sb.w), 0.f);
    }

    // ---- layer 2: 64 -> 64 ----
#pragma unroll
    for (int c = 0; c < 64; ++c) acc[c] = 0.f;
#pragma unroll
    for (int kk = 0; kk < 64; ++kk) {
        const float hv = h[kk];
        const float* wr = W2 + kk * 64;
#pragma unroll
        for (int c = 0; c < 64; ++c) acc[c] = fmaf(hv, wr[c], acc[c]);
    }
#pragma unroll
    for (int c4 = 0; c4 < 16; ++c4) {
        float4 sc = *(const float4*)&sscale[64 + c4 * 4];
        float4 sb = *(const float4*)&sbias[64 + c4 * 4];
        h[c4*4+0] = fmaxf(fmaf(acc[c4*4+0], sc.x, sb.x), 0.f);
        h[c4*4+1] = fmaxf(fmaf(acc[c4*4+1], sc.y, sb.y), 0.f);
        h[c4*4+2] = fmaxf(fmaf(acc[c4*4+2], sc.z, sb.z), 0.f);
        h[c4*4+3] = fmaxf(fmaf(acc[c4*4+3], sc.w, sb.w), 0.f);
    }

    // ---- layer 3: 64 -> 128 ----
    float acc3[128];
#pragma unroll
    for (int c = 0; c < 128; ++c) acc3[c] = 0.f;
#pragma unroll
    for (int kk = 0; kk < 64; ++kk) {
        const float hv = h[kk];
        const float* wr = W3 + kk * 128;
#pragma unroll
        for (int c = 0; c < 128; ++c) acc3[c] = fmaf(hv, wr[c], acc3[c]);
    }
#pragma unroll
    for (int c4 = 0; c4 < 32; ++c4) {
        float4 sc = *(const float4*)&sscale[128 + c4 * 4];
        float4 sb = *(const float4*)&sbias[128 + c4 * 4];
        acc3[c4*4+0] = fmaxf(fmaf(acc3[c4*4+0], sc.x, sb.x), 0.f);
        acc3[c4*4+1] = fmaxf(fmaf(acc3[c4*4+1], sc.y, sb.y), 0.f);
        acc3[c4*4+2] = fmaxf(fmaf(acc3[c4*4+2], sc.z, sb.z), 0.f);
        acc3[c4*4+3] = fmaxf(fmaf(acc3[c4*4+3], sc.w, sb.w), 0.f);
    }
    if (!valid) {
#pragma unroll
        for (int c = 0; c < 128; ++c) acc3[c] = -FLT_MAX;
    }

    // ---- max over 32 neighbors = 32-lane half-wave DPP reduce ----
#pragma unroll
    for (int c = 0; c < 128; ++c) acc3[c] = half_max_f32(acc3[c]);

    if (k == 0) {                              // lanes 0 and 32: group leaders
        float* op = out + (size_t)cid * 128;
#pragma unroll
        for (int c4 = 0; c4 < 32; ++c4) {
            *(float4*)(op + c4 * 4) =
                make_float4(acc3[c4*4+0], acc3[c4*4+1], acc3[c4*4+2], acc3[c4*4+3]);
        }
    }
}

extern "C" void kernel_launch(void* const* d_in, const int* in_sizes, int n_in,
                              void* d_out, int out_size, void* d_ws, size_t ws_size,
                              hipStream_t stream) {
    const float* x   = (const float*)d_in[0];
    const float* pos = (const float*)d_in[1];
    const float* W1  = (const float*)d_in[2];
    const float* g1  = (const float*)d_in[3];
    const float* b1  = (const float*)d_in[4];
    const float* rm1 = (const float*)d_in[5];
    const float* rv1 = (const float*)d_in[6];
    const float* W2  = (const float*)d_in[7];
    const float* g2  = (const float*)d_in[8];
    const float* b2  = (const float*)d_in[9];
    const float* rm2 = (const float*)d_in[10];
    const float* rv2 = (const float*)d_in[11];
    const float* W3  = (const float*)d_in[12];
    const float* g3  = (const float*)d_in[13];
    const float* b3  = (const float*)d_in[14];
    const float* rm3 = (const float*)d_in[15];
    const float* rv3 = (const float*)d_in[16];

    float* out  = (float*)d_out;
    float* cpos = out + OUT_X;          // second output region
    int*   nidx = (int*)d_ws;           // B*M*K ints = 2 MiB scratch

    fps_kernel<<<dim3(BATCH), dim3(512), 0, stream>>>(pos, cpos);
    ballq_kernel<<<dim3(BATCH * MCENT / 4), dim3(256), 0, stream>>>(pos, cpos, nidx);
    mlp_kernel<<<dim3(BATCH * MCENT / 8), dim3(256), 0, stream>>>(
        x, pos, W1, g1, b1, rm1, rv1, W2, g2, b2, rm2, rv2,
        W3, g3, b3, rm3, rv3, cpos, nidx, out);
}

// Round 11
// 2433.748 us; speedup vs baseline: 1.2529x; 1.2529x over previous
//
#include <hip/hip_runtime.h>
#include <hip/hip_bf16.h>
#include <float.h>
#include <math.h>

#define BATCH 16
#define NPTS  4096
#define CIN   64
#define MCENT 1024
#define KNB   32
#define OUT_X (BATCH * MCENT * 128)

// ---- exact (non-contracted) f32 ops: bitwise-match numpy's separate roundings ----
__device__ __forceinline__ float f_sub(float a, float b){ float r; asm("v_sub_f32 %0, %1, %2" : "=v"(r) : "v"(a), "v"(b)); return r; }
__device__ __forceinline__ float f_mul(float a, float b){ float r; asm("v_mul_f32 %0, %1, %2" : "=v"(r) : "v"(a), "v"(b)); return r; }
__device__ __forceinline__ float f_add(float a, float b){ float r; asm("v_add_f32 %0, %1, %2" : "=v"(r) : "v"(a), "v"(b)); return r; }

__device__ __forceinline__ float dist2_exact(float px, float py, float pz,
                                             float lx, float ly, float lz) {
    float dx = f_sub(px, lx), dy = f_sub(py, ly), dz = f_sub(pz, lz);
    return f_add(f_add(f_mul(dx, dx), f_mul(dy, dy)), f_mul(dz, dz));
}

// DPP max step (bound_ctrl=false, full masks: OOB lanes fall back to old = x, fmax(x,x)=x safe)
template <int CTRL>
__device__ __forceinline__ float dpp_max(float x) {
    int xi = __float_as_int(x);
    int yi = __builtin_amdgcn_update_dpp(xi, xi, CTRL, 0xF, 0xF, false);
    return fmaxf(x, __int_as_float(yi));
}
// max over each 32-lane half (no xor32)
__device__ __forceinline__ float half_max_f32(float v) {
    v = dpp_max<0xB1>(v);   // quad_perm xor1
    v = dpp_max<0x4E>(v);   // quad_perm xor2
    v = dpp_max<0x141>(v);  // row_half_mirror (4-group merge)
    v = dpp_max<0x140>(v);  // row_mirror (8-group merge)
    int s = __builtin_amdgcn_ds_swizzle(__float_as_int(v), 0x401F); // xor16 (within 32)
    return fmaxf(v, __int_as_float(s));
}
// full wave max
__device__ __forceinline__ float wave_max_f32(float v) {
    v = half_max_f32(v);
    float a = v, b = v;
    asm("v_permlane32_swap_b32 %0, %1" : "+v"(a), "+v"(b));  // xor32 (VALU)
    return fmaxf(a, b);
}

// ================= K1: farthest point sampling =================
// one block/batch; 512 threads; thread owns 8 contiguous points in registers.
// Per iteration: in-wave argmax (DPP + ballot/shfl), lane0 writes packed u64 key,
// ONE barrier, everyone scans the 8 keys (broadcast reads) -> winner.
__global__ __launch_bounds__(512, 1) void fps_kernel(
    const float* __restrict__ pos, float* __restrict__ cpos)
{
    __shared__ __align__(16) float4 sp[NPTS];                 // 64KB xyz+pad
    __shared__ __align__(16) unsigned long long swkey[2][8];
    __shared__ int widxarr[MCENT];

    const int b = blockIdx.x;
    const int t = threadIdx.x;
    const int lane = t & 63, wv = t >> 6;
    const float* pb = pos + (size_t)b * NPTS * 3;

    float px[8], py[8], pz[8], mind[8];
    {
        const float4* src = (const float4*)(pb + t * 24);
        float v[24];
#pragma unroll
        for (int q = 0; q < 6; ++q) {
            float4 f = src[q];
            v[q*4+0]=f.x; v[q*4+1]=f.y; v[q*4+2]=f.z; v[q*4+3]=f.w;
        }
#pragma unroll
        for (int jj = 0; jj < 8; ++jj) {
            int n = t * 8 + jj;
            px[jj]=v[jj*3+0]; py[jj]=v[jj*3+1]; pz[jj]=v[jj*3+2];
            sp[n] = make_float4(px[jj], py[jj], pz[jj], 0.f);
            mind[jj] = 1e10f;
        }
    }
    if (t == 0) widxarr[0] = 0;
    __syncthreads();

    int w = 0;
    for (int i = 1; i < MCENT; ++i) {
        float4 L = sp[w];                       // broadcast b128
#pragma unroll
        for (int jj = 0; jj < 8; ++jj) {
            float d = dist2_exact(px[jj], py[jj], pz[jj], L.x, L.y, L.z);
            mind[jj] = fminf(mind[jj], d);
        }
        float tmax = fmaxf(fmaxf(fmaxf(mind[0],mind[1]), fmaxf(mind[2],mind[3])),
                           fmaxf(fmaxf(mind[4],mind[5]), fmaxf(mind[6],mind[7])));
        float wmax = wave_max_f32(tmax);
        int cand = 0;
#pragma unroll
        for (int jj = 7; jj >= 0; --jj)
            if (mind[jj] == wmax) cand = t * 8 + jj;      // smallest matching j wins
        unsigned long long msk = __ballot(tmax == wmax);  // nonzero by construction
        int first = __ffsll(msk) - 1;
        int candw = __shfl(cand, first);
        if (lane == 0)
            swkey[i & 1][wv] = ((unsigned long long)__float_as_uint(wmax) << 32)
                             | (unsigned)(NPTS - 1 - candw);
        __syncthreads();                        // the only barrier per iteration
        unsigned long long best = swkey[i & 1][0];
#pragma unroll
        for (int q = 1; q < 8; ++q) {
            unsigned long long o = swkey[i & 1][q];
            best = o > best ? o : best;         // larger dist wins; tie -> smaller index
        }
        w = (NPTS - 1) - (int)(unsigned)(best & 0xFFFFFFFFull);
        if (t == 0) widxarr[i] = w;
    }
    __syncthreads();
#pragma unroll
    for (int e = 0; e < 2; ++e) {
        int c = t + e * 512;
        float4 P = sp[widxarr[c]];
        float* cp = cpos + ((size_t)b * MCENT + c) * 3;
        cp[0] = P.x; cp[1] = P.y; cp[2] = P.z;
    }
}

// ================= K2: ball query (first K in index order within radius) =================
__global__ __launch_bounds__(256) void ballq_kernel(
    const float* __restrict__ pos, const float* __restrict__ cpos,
    int* __restrict__ nidx)
{
    const int wid  = blockIdx.x * 4 + (threadIdx.x >> 6);
    const int lane = threadIdx.x & 63;
    const int b    = wid >> 10;
    const float* pb = pos + (size_t)b * NPTS * 3;
    const float cx = cpos[wid * 3 + 0];
    const float cy = cpos[wid * 3 + 1];
    const float cz = cpos[wid * 3 + 2];
    const float R2 = (float)(0.2 * 0.2);
    int* outp = nidx + (size_t)wid * KNB;

    int cnt = 0;
    for (int j0 = 0; j0 < NPTS; j0 += 64) {
        int j = j0 + lane;
        float x = pb[j * 3 + 0], y = pb[j * 3 + 1], z = pb[j * 3 + 2];
        float d = dist2_exact(x, y, z, cx, cy, cz);
        bool valid = (d <= R2);
        unsigned long long msk = __ballot(valid);
        if (valid) {
            int rank = cnt + __popcll(msk & ((1ull << lane) - 1ull));
            if (rank < KNB) outp[rank] = j;
        }
        cnt += __popcll(msk);
        if (cnt >= KNB) break;
    }
    int nv = cnt < KNB ? cnt : KNB;
    if (lane >= nv && lane < KNB) outp[lane] = -1;
}

// ================= K3: gather + shared MLP + DPP max-pool =================
// 256 threads = 8 centroids x 32 neighbor-rows; one row per thread.
// Activation row in registers; layer 3 computed in TWO 64-channel passes that
// reuse acc[64] and fold BN+ReLU+mask+pool+store per pass -> peak live regs
// ~h[67]+acc[64] ≈ 140 (round 9's acc3[128] spilled: VGPR=140 + 31GB scratch).
__global__ __launch_bounds__(256, 1) void mlp_kernel(
    const float* __restrict__ x, const float* __restrict__ pos,
    const float* __restrict__ W1, const float* __restrict__ g1, const float* __restrict__ b1,
    const float* __restrict__ rm1, const float* __restrict__ rv1,
    const float* __restrict__ W2, const float* __restrict__ g2, const float* __restrict__ b2,
    const float* __restrict__ rm2, const float* __restrict__ rv2,
    const float* __restrict__ W3, const float* __restrict__ g3, const float* __restrict__ b3,
    const float* __restrict__ rm3, const float* __restrict__ rv3,
    const float* __restrict__ cpos, const int* __restrict__ nidx,
    float* __restrict__ out)
{
    __shared__ __align__(16) float sscale[256];
    __shared__ __align__(16) float sbias[256];

    const int t   = threadIdx.x;
    const int g   = t >> 5;               // centroid within block
    const int k   = t & 31;               // neighbor slot (= lane&31)
    const int cid0 = blockIdx.x * 8;
    const int cid  = cid0 + g;
    const int b    = cid >> 10;

    // fused BN(eval) constants: y = h*scale + bias
    {
        float gg, bb, rm, rv;
        if (t < 64)       { gg = g1[t];     bb = b1[t];     rm = rm1[t];     rv = rv1[t]; }
        else if (t < 128) { int c = t - 64;  gg = g2[c]; bb = b2[c]; rm = rm2[c]; rv = rv2[c]; }
        else              { int c = t - 128; gg = g3[c]; bb = b3[c]; rm = rm3[c]; rv = rv3[c]; }
        float s = gg / sqrtf(rv + 1e-5f);
        sscale[t] = s;
        sbias[t]  = bb - rm * s;
    }

    const int j = nidx[(size_t)cid * KNB + k];
    const bool valid = (j >= 0);
    float h[67];
    if (valid) {
        const float4* xr = (const float4*)(x + ((size_t)b * NPTS + j) * CIN);
#pragma unroll
        for (int q = 0; q < 16; ++q) {
            float4 v = xr[q];
            h[q*4+0]=v.x; h[q*4+1]=v.y; h[q*4+2]=v.z; h[q*4+3]=v.w;
        }
        const float* pr = pos + ((size_t)b * NPTS + j) * 3;
        h[64] = f_sub(pr[0], cpos[cid * 3 + 0]);
        h[65] = f_sub(pr[1], cpos[cid * 3 + 1]);
        h[66] = f_sub(pr[2], cpos[cid * 3 + 2]);
    } else {
#pragma unroll
        for (int q = 0; q < 67; ++q) h[q] = 0.f;
    }
    __syncthreads();   // sscale/sbias ready

    float acc[64];
    // ---- layer 1: 67 -> 64 ----
#pragma unroll
    for (int c = 0; c < 64; ++c) acc[c] = 0.f;
#pragma unroll
    for (int kk = 0; kk < 67; ++kk) {
        const float hv = h[kk];
        const float* wr = W1 + kk * 64;     // wave-uniform -> s_load
#pragma unroll
        for (int c = 0; c < 64; ++c) acc[c] = fmaf(hv, wr[c], acc[c]);
    }
#pragma unroll
    for (int c4 = 0; c4 < 16; ++c4) {
        float4 sc = *(const float4*)&sscale[c4 * 4];
        float4 sb = *(const float4*)&sbias[c4 * 4];
        h[c4*4+0] = fmaxf(fmaf(acc[c4*4+0], sc.x, sb.x), 0.f);
        h[c4*4+1] = fmaxf(fmaf(acc[c4*4+1], sc.y, sb.y), 0.f);
        h[c4*4+2] = fmaxf(fmaf(acc[c4*4+2], sc.z, sb.z), 0.f);
        h[c4*4+3] = fmaxf(fmaf(acc[c4*4+3], sc.w, sb.w), 0.f);
    }

    // ---- layer 2: 64 -> 64 ----
#pragma unroll
    for (int c = 0; c < 64; ++c) acc[c] = 0.f;
#pragma unroll
    for (int kk = 0; kk < 64; ++kk) {
        const float hv = h[kk];
        const float* wr = W2 + kk * 64;
#pragma unroll
        for (int c = 0; c < 64; ++c) acc[c] = fmaf(hv, wr[c], acc[c]);
    }
#pragma unroll
    for (int c4 = 0; c4 < 16; ++c4) {
        float4 sc = *(const float4*)&sscale[64 + c4 * 4];
        float4 sb = *(const float4*)&sbias[64 + c4 * 4];
        h[c4*4+0] = fmaxf(fmaf(acc[c4*4+0], sc.x, sb.x), 0.f);
        h[c4*4+1] = fmaxf(fmaf(acc[c4*4+1], sc.y, sb.y), 0.f);
        h[c4*4+2] = fmaxf(fmaf(acc[c4*4+2], sc.z, sb.z), 0.f);
        h[c4*4+3] = fmaxf(fmaf(acc[c4*4+3], sc.w, sb.w), 0.f);
    }

    // ---- layer 3: 64 -> 128, two 64-channel passes reusing acc[64] ----
#pragma unroll
    for (int half = 0; half < 2; ++half) {
#pragma unroll
        for (int c = 0; c < 64; ++c) acc[c] = 0.f;
#pragma unroll
        for (int kk = 0; kk < 64; ++kk) {
            const float hv = h[kk];
            const float* wr = W3 + kk * 128 + half * 64;
#pragma unroll
            for (int c = 0; c < 64; ++c) acc[c] = fmaf(hv, wr[c], acc[c]);
        }
        // BN + ReLU + invalid-mask + half-wave DPP max-pool + leader store
#pragma unroll
        for (int c4 = 0; c4 < 16; ++c4) {
            float4 sc = *(const float4*)&sscale[128 + half * 64 + c4 * 4];
            float4 sb = *(const float4*)&sbias[128 + half * 64 + c4 * 4];
            float v0 = fmaxf(fmaf(acc[c4*4+0], sc.x, sb.x), 0.f);
            float v1 = fmaxf(fmaf(acc[c4*4+1], sc.y, sb.y), 0.f);
            float v2 = fmaxf(fmaf(acc[c4*4+2], sc.z, sb.z), 0.f);
            float v3 = fmaxf(fmaf(acc[c4*4+3], sc.w, sb.w), 0.f);
            if (!valid) { v0 = -FLT_MAX; v1 = -FLT_MAX; v2 = -FLT_MAX; v3 = -FLT_MAX; }
            acc[c4*4+0] = half_max_f32(v0);
            acc[c4*4+1] = half_max_f32(v1);
            acc[c4*4+2] = half_max_f32(v2);
            acc[c4*4+3] = half_max_f32(v3);
        }
        if (k == 0) {                          // lanes 0 and 32: group leaders
            float* op = out + (size_t)cid * 128 + half * 64;
#pragma unroll
            for (int c4 = 0; c4 < 16; ++c4) {
                *(float4*)(op + c4 * 4) =
                    make_float4(acc[c4*4+0], acc[c4*4+1], acc[c4*4+2], acc[c4*4+3]);
            }
        }
    }
}

extern "C" void kernel_launch(void* const* d_in, const int* in_sizes, int n_in,
                              void* d_out, int out_size, void* d_ws, size_t ws_size,
                              hipStream_t stream) {
    const float* x   = (const float*)d_in[0];
    const float* pos = (const float*)d_in[1];
    const float* W1  = (const float*)d_in[2];
    const float* g1  = (const float*)d_in[3];
    const float* b1  = (const float*)d_in[4];
    const float* rm1 = (const float*)d_in[5];
    const float* rv1 = (const float*)d_in[6];
    const float* W2  = (const float*)d_in[7];
    const float* g2  = (const float*)d_in[8];
    const float* b2  = (const float*)d_in[9];
    const float* rm2 = (const float*)d_in[10];
    const float* rv2 = (const float*)d_in[11];
    const float* W3  = (const float*)d_in[12];
    const float* g3  = (const float*)d_in[13];
    const float* b3  = (const float*)d_in[14];
    const float* rm3 = (const float*)d_in[15];
    const float* rv3 = (const float*)d_in[16];

    float* out  = (float*)d_out;
    float* cpos = out + OUT_X;          // second output region
    int*   nidx = (int*)d_ws;           // B*M*K ints = 2 MiB scratch

    fps_kernel<<<dim3(BATCH), dim3(512), 0, stream>>>(pos, cpos);
    ballq_kernel<<<dim3(BATCH * MCENT / 4), dim3(256), 0, stream>>>(pos, cpos, nidx);
    mlp_kernel<<<dim3(BATCH * MCENT / 8), dim3(256), 0, stream>>>(
        x, pos, W1, g1, b1, rm1, rv1, W2, g2, b2, rm2, rv2,
        W3, g3, b3, rm3, rv3, cpos, nidx, out);
}

// Round 12
// 2201.906 us; speedup vs baseline: 1.3848x; 1.1053x over previous
//
#include <hip/hip_runtime.h>
#include <hip/hip_bf16.h>
#include <float.h>
#include <math.h>

#define BATCH 16
#define NPTS  4096
#define CIN   64
#define MCENT 1024
#define KNB   32
#define OUT_X (BATCH * MCENT * 128)

// ---- exact (non-contracted) f32 ops: bitwise-match numpy's separate roundings ----
__device__ __forceinline__ float f_sub(float a, float b){ float r; asm("v_sub_f32 %0, %1, %2" : "=v"(r) : "v"(a), "v"(b)); return r; }
__device__ __forceinline__ float f_mul(float a, float b){ float r; asm("v_mul_f32 %0, %1, %2" : "=v"(r) : "v"(a), "v"(b)); return r; }
__device__ __forceinline__ float f_add(float a, float b){ float r; asm("v_add_f32 %0, %1, %2" : "=v"(r) : "v"(a), "v"(b)); return r; }

__device__ __forceinline__ float dist2_exact(float px, float py, float pz,
                                             float lx, float ly, float lz) {
    float dx = f_sub(px, lx), dy = f_sub(py, ly), dz = f_sub(pz, lz);
    return f_add(f_add(f_mul(dx, dx), f_mul(dy, dy)), f_mul(dz, dz));
}

// DPP max step (bound_ctrl=false, full masks)
template <int CTRL>
__device__ __forceinline__ float dpp_max(float x) {
    int xi = __float_as_int(x);
    int yi = __builtin_amdgcn_update_dpp(xi, xi, CTRL, 0xF, 0xF, false);
    return fmaxf(x, __int_as_float(yi));
}
// max over each 32-lane half
__device__ __forceinline__ float half_max_f32(float v) {
    v = dpp_max<0xB1>(v);   // quad_perm xor1
    v = dpp_max<0x4E>(v);   // quad_perm xor2
    v = dpp_max<0x141>(v);  // row_half_mirror
    v = dpp_max<0x140>(v);  // row_mirror
    int s = __builtin_amdgcn_ds_swizzle(__float_as_int(v), 0x401F); // xor16
    return fmaxf(v, __int_as_float(s));
}
// full wave max
__device__ __forceinline__ float wave_max_f32(float v) {
    v = half_max_f32(v);
    float a = v, b = v;
    asm("v_permlane32_swap_b32 %0, %1" : "+v"(a), "+v"(b));  // xor32 (VALU)
    return fmaxf(a, b);
}

// ================= K1: farthest point sampling (unchanged from round 7/9) =================
__global__ __launch_bounds__(512, 1) void fps_kernel(
    const float* __restrict__ pos, float* __restrict__ cpos)
{
    __shared__ __align__(16) float4 sp[NPTS];
    __shared__ __align__(16) unsigned long long swkey[2][8];
    __shared__ int widxarr[MCENT];

    const int b = blockIdx.x;
    const int t = threadIdx.x;
    const int lane = t & 63, wv = t >> 6;
    const float* pb = pos + (size_t)b * NPTS * 3;

    float px[8], py[8], pz[8], mind[8];
    {
        const float4* src = (const float4*)(pb + t * 24);
        float v[24];
#pragma unroll
        for (int q = 0; q < 6; ++q) {
            float4 f = src[q];
            v[q*4+0]=f.x; v[q*4+1]=f.y; v[q*4+2]=f.z; v[q*4+3]=f.w;
        }
#pragma unroll
        for (int jj = 0; jj < 8; ++jj) {
            int n = t * 8 + jj;
            px[jj]=v[jj*3+0]; py[jj]=v[jj*3+1]; pz[jj]=v[jj*3+2];
            sp[n] = make_float4(px[jj], py[jj], pz[jj], 0.f);
            mind[jj] = 1e10f;
        }
    }
    if (t == 0) widxarr[0] = 0;
    __syncthreads();

    int w = 0;
    for (int i = 1; i < MCENT; ++i) {
        float4 L = sp[w];
#pragma unroll
        for (int jj = 0; jj < 8; ++jj) {
            float d = dist2_exact(px[jj], py[jj], pz[jj], L.x, L.y, L.z);
            mind[jj] = fminf(mind[jj], d);
        }
        float tmax = fmaxf(fmaxf(fmaxf(mind[0],mind[1]), fmaxf(mind[2],mind[3])),
                           fmaxf(fmaxf(mind[4],mind[5]), fmaxf(mind[6],mind[7])));
        float wmax = wave_max_f32(tmax);
        int cand = 0;
#pragma unroll
        for (int jj = 7; jj >= 0; --jj)
            if (mind[jj] == wmax) cand = t * 8 + jj;
        unsigned long long msk = __ballot(tmax == wmax);
        int first = __ffsll(msk) - 1;
        int candw = __shfl(cand, first);
        if (lane == 0)
            swkey[i & 1][wv] = ((unsigned long long)__float_as_uint(wmax) << 32)
                             | (unsigned)(NPTS - 1 - candw);
        __syncthreads();
        unsigned long long best = swkey[i & 1][0];
#pragma unroll
        for (int q = 1; q < 8; ++q) {
            unsigned long long o = swkey[i & 1][q];
            best = o > best ? o : best;
        }
        w = (NPTS - 1) - (int)(unsigned)(best & 0xFFFFFFFFull);
        if (t == 0) widxarr[i] = w;
    }
    __syncthreads();
#pragma unroll
    for (int e = 0; e < 2; ++e) {
        int c = t + e * 512;
        float4 P = sp[widxarr[c]];
        float* cp = cpos + ((size_t)b * MCENT + c) * 3;
        cp[0] = P.x; cp[1] = P.y; cp[2] = P.z;
    }
}

// ================= K2: ball query (unchanged) =================
__global__ __launch_bounds__(256) void ballq_kernel(
    const float* __restrict__ pos, const float* __restrict__ cpos,
    int* __restrict__ nidx)
{
    const int wid  = blockIdx.x * 4 + (threadIdx.x >> 6);
    const int lane = threadIdx.x & 63;
    const int b    = wid >> 10;
    const float* pb = pos + (size_t)b * NPTS * 3;
    const float cx = cpos[wid * 3 + 0];
    const float cy = cpos[wid * 3 + 1];
    const float cz = cpos[wid * 3 + 2];
    const float R2 = (float)(0.2 * 0.2);
    int* outp = nidx + (size_t)wid * KNB;

    int cnt = 0;
    for (int j0 = 0; j0 < NPTS; j0 += 64) {
        int j = j0 + lane;
        float x = pb[j * 3 + 0], y = pb[j * 3 + 1], z = pb[j * 3 + 2];
        float d = dist2_exact(x, y, z, cx, cy, cz);
        bool valid = (d <= R2);
        unsigned long long msk = __ballot(valid);
        if (valid) {
            int rank = cnt + __popcll(msk & ((1ull << lane) - 1ull));
            if (rank < KNB) outp[rank] = j;
        }
        cnt += __popcll(msk);
        if (cnt >= KNB) break;
    }
    int nv = cnt < KNB ? cnt : KNB;
    if (lane >= nv && lane < KNB) outp[lane] = -1;
}

// ================= K3: gather + shared MLP + DPP max-pool (anti-spill v3) =================
// 256 threads = 8 centroids x 32 rows. Peak live regs ~100-115 by construction:
//  L1 streams x from global (no h[67] held), full acc[64].
//  L2 = two 32-ch passes; pass A parked in a private LDS stash (no barrier needed).
//  L3 = four 32-ch passes, BN+mask+pool+store folded per pass.
__global__ __launch_bounds__(256, 1) void mlp_kernel(
    const float* __restrict__ x, const float* __restrict__ pos,
    const float* __restrict__ W1, const float* __restrict__ g1, const float* __restrict__ b1,
    const float* __restrict__ rm1, const float* __restrict__ rv1,
    const float* __restrict__ W2, const float* __restrict__ g2, const float* __restrict__ b2,
    const float* __restrict__ rm2, const float* __restrict__ rv2,
    const float* __restrict__ W3, const float* __restrict__ g3, const float* __restrict__ b3,
    const float* __restrict__ rm3, const float* __restrict__ rv3,
    const float* __restrict__ cpos, const int* __restrict__ nidx,
    float* __restrict__ out)
{
    __shared__ __align__(16) float sscale[256];
    __shared__ __align__(16) float sbias[256];
    __shared__ float stash[256 * 33];   // per-thread 32-float slot, stride 33 -> conflict-free b32

    const int t   = threadIdx.x;
    const int g   = t >> 5;
    const int k   = t & 31;
    const int cid0 = blockIdx.x * 8;
    const int cid  = cid0 + g;
    const int b    = cid >> 10;

    {
        float gg, bb, rm, rv;
        if (t < 64)       { gg = g1[t];     bb = b1[t];     rm = rm1[t];     rv = rv1[t]; }
        else if (t < 128) { int c = t - 64;  gg = g2[c]; bb = b2[c]; rm = rm2[c]; rv = rv2[c]; }
        else              { int c = t - 128; gg = g3[c]; bb = b3[c]; rm = rm3[c]; rv = rv3[c]; }
        float s = gg / sqrtf(rv + 1e-5f);
        sscale[t] = s;
        sbias[t]  = bb - rm * s;
    }

    const int j = nidx[(size_t)cid * KNB + k];
    const bool valid = (j >= 0);
    const int js = valid ? j : 0;                 // safe row; garbage masked at the end
    const float4* xr = (const float4*)(x + ((size_t)b * NPTS + js) * CIN);
    const float* pr  = pos + ((size_t)b * NPTS + js) * 3;
    const float rpx = f_sub(pr[0], cpos[cid * 3 + 0]);
    const float rpy = f_sub(pr[1], cpos[cid * 3 + 1]);
    const float rpz = f_sub(pr[2], cpos[cid * 3 + 2]);

    __syncthreads();   // sscale/sbias ready

    // ---- layer 1: 67 -> 64, streaming x (live: acc[64] + stream temps) ----
    float acc[64];
#pragma unroll
    for (int c = 0; c < 64; ++c) acc[c] = 0.f;
#pragma unroll
    for (int q = 0; q < 16; ++q) {
        const float4 v = xr[q];
        { const float* wr = W1 + (q * 4 + 0) * 64;
#pragma unroll
          for (int c = 0; c < 64; ++c) acc[c] = fmaf(v.x, wr[c], acc[c]); }
        { const float* wr = W1 + (q * 4 + 1) * 64;
#pragma unroll
          for (int c = 0; c < 64; ++c) acc[c] = fmaf(v.y, wr[c], acc[c]); }
        { const float* wr = W1 + (q * 4 + 2) * 64;
#pragma unroll
          for (int c = 0; c < 64; ++c) acc[c] = fmaf(v.z, wr[c], acc[c]); }
        { const float* wr = W1 + (q * 4 + 3) * 64;
#pragma unroll
          for (int c = 0; c < 64; ++c) acc[c] = fmaf(v.w, wr[c], acc[c]); }
    }
    { const float* wr = W1 + 64 * 64;
#pragma unroll
      for (int c = 0; c < 64; ++c) acc[c] = fmaf(rpx, wr[c], acc[c]); }
    { const float* wr = W1 + 65 * 64;
#pragma unroll
      for (int c = 0; c < 64; ++c) acc[c] = fmaf(rpy, wr[c], acc[c]); }
    { const float* wr = W1 + 66 * 64;
#pragma unroll
      for (int c = 0; c < 64; ++c) acc[c] = fmaf(rpz, wr[c], acc[c]); }

    float h[64];
#pragma unroll
    for (int c4 = 0; c4 < 16; ++c4) {
        float4 sc = *(const float4*)&sscale[c4 * 4];
        float4 sb = *(const float4*)&sbias[c4 * 4];
        h[c4*4+0] = fmaxf(fmaf(acc[c4*4+0], sc.x, sb.x), 0.f);
        h[c4*4+1] = fmaxf(fmaf(acc[c4*4+1], sc.y, sb.y), 0.f);
        h[c4*4+2] = fmaxf(fmaf(acc[c4*4+2], sc.z, sb.z), 0.f);
        h[c4*4+3] = fmaxf(fmaf(acc[c4*4+3], sc.w, sb.w), 0.f);
    }

    // ---- layer 2 pass A: channels 0..31 -> LDS stash (live: h[64]+a2[32]) ----
    float a2[32];
#pragma unroll
    for (int c = 0; c < 32; ++c) a2[c] = 0.f;
#pragma unroll
    for (int kk = 0; kk < 64; ++kk) {
        const float hv = h[kk];
        const float* wr = W2 + kk * 64;
#pragma unroll
        for (int c = 0; c < 32; ++c) a2[c] = fmaf(hv, wr[c], a2[c]);
    }
#pragma unroll
    for (int c4 = 0; c4 < 8; ++c4) {
        float4 sc = *(const float4*)&sscale[64 + c4 * 4];
        float4 sb = *(const float4*)&sbias[64 + c4 * 4];
        stash[t * 33 + c4*4+0] = fmaxf(fmaf(a2[c4*4+0], sc.x, sb.x), 0.f);
        stash[t * 33 + c4*4+1] = fmaxf(fmaf(a2[c4*4+1], sc.y, sb.y), 0.f);
        stash[t * 33 + c4*4+2] = fmaxf(fmaf(a2[c4*4+2], sc.z, sb.z), 0.f);
        stash[t * 33 + c4*4+3] = fmaxf(fmaf(a2[c4*4+3], sc.w, sb.w), 0.f);
    }

    // ---- layer 2 pass B: channels 32..63 -> h[32..63] (h fully consumed first) ----
#pragma unroll
    for (int c = 0; c < 32; ++c) a2[c] = 0.f;
#pragma unroll
    for (int kk = 0; kk < 64; ++kk) {
        const float hv = h[kk];
        const float* wr = W2 + kk * 64 + 32;
#pragma unroll
        for (int c = 0; c < 32; ++c) a2[c] = fmaf(hv, wr[c], a2[c]);
    }
#pragma unroll
    for (int c4 = 0; c4 < 8; ++c4) {
        float4 sc = *(const float4*)&sscale[96 + c4 * 4];
        float4 sb = *(const float4*)&sbias[96 + c4 * 4];
        h[32 + c4*4+0] = fmaxf(fmaf(a2[c4*4+0], sc.x, sb.x), 0.f);
        h[32 + c4*4+1] = fmaxf(fmaf(a2[c4*4+1], sc.y, sb.y), 0.f);
        h[32 + c4*4+2] = fmaxf(fmaf(a2[c4*4+2], sc.z, sb.z), 0.f);
        h[32 + c4*4+3] = fmaxf(fmaf(a2[c4*4+3], sc.w, sb.w), 0.f);
    }
#pragma unroll
    for (int c = 0; c < 32; ++c) h[c] = stash[t * 33 + c];   // same-thread RAW, no barrier

    // ---- layer 3: 64 -> 128 in four 32-ch passes; pool+store folded ----
#pragma unroll
    for (int p = 0; p < 4; ++p) {
#pragma unroll
        for (int c = 0; c < 32; ++c) a2[c] = 0.f;
#pragma unroll
        for (int kk = 0; kk < 64; ++kk) {
            const float hv = h[kk];
            const float* wr = W3 + kk * 128 + p * 32;
#pragma unroll
            for (int c = 0; c < 32; ++c) a2[c] = fmaf(hv, wr[c], a2[c]);
        }
#pragma unroll
        for (int c4 = 0; c4 < 8; ++c4) {
            float4 sc = *(const float4*)&sscale[128 + p * 32 + c4 * 4];
            float4 sb = *(const float4*)&sbias[128 + p * 32 + c4 * 4];
            float v0 = fmaxf(fmaf(a2[c4*4+0], sc.x, sb.x), 0.f);
            float v1 = fmaxf(fmaf(a2[c4*4+1], sc.y, sb.y), 0.f);
            float v2 = fmaxf(fmaf(a2[c4*4+2], sc.z, sb.z), 0.f);
            float v3 = fmaxf(fmaf(a2[c4*4+3], sc.w, sb.w), 0.f);
            if (!valid) { v0 = -FLT_MAX; v1 = -FLT_MAX; v2 = -FLT_MAX; v3 = -FLT_MAX; }
            a2[c4*4+0] = half_max_f32(v0);
            a2[c4*4+1] = half_max_f32(v1);
            a2[c4*4+2] = half_max_f32(v2);
            a2[c4*4+3] = half_max_f32(v3);
        }
        if (k == 0) {                          // lanes 0 and 32: group leaders
            float* op = out + (size_t)cid * 128 + p * 32;
#pragma unroll
            for (int c4 = 0; c4 < 8; ++c4) {
                *(float4*)(op + c4 * 4) =
                    make_float4(a2[c4*4+0], a2[c4*4+1], a2[c4*4+2], a2[c4*4+3]);
            }
        }
    }
}

extern "C" void kernel_launch(void* const* d_in, const int* in_sizes, int n_in,
                              void* d_out, int out_size, void* d_ws, size_t ws_size,
                              hipStream_t stream) {
    const float* x   = (const float*)d_in[0];
    const float* pos = (const float*)d_in[1];
    const float* W1  = (const float*)d_in[2];
    const float* g1  = (const float*)d_in[3];
    const float* b1  = (const float*)d_in[4];
    const float* rm1 = (const float*)d_in[5];
    const float* rv1 = (const float*)d_in[6];
    const float* W2  = (const float*)d_in[7];
    const float* g2  = (const float*)d_in[8];
    const float* b2  = (const float*)d_in[9];
    const float* rm2 = (const float*)d_in[10];
    const float* rv2 = (const float*)d_in[11];
    const float* W3  = (const float*)d_in[12];
    const float* g3  = (const float*)d_in[13];
    const float* b3  = (const float*)d_in[14];
    const float* rm3 = (const float*)d_in[15];
    const float* rv3 = (const float*)d_in[16];

    float* out  = (float*)d_out;
    float* cpos = out + OUT_X;          // second output region
    int*   nidx = (int*)d_ws;           // B*M*K ints = 2 MiB scratch

    fps_kernel<<<dim3(BATCH), dim3(512), 0, stream>>>(pos, cpos);
    ballq_kernel<<<dim3(BATCH * MCENT / 4), dim3(256), 0, stream>>>(pos, cpos, nidx);
    mlp_kernel<<<dim3(BATCH * MCENT / 8), dim3(256), 0, stream>>>(
        x, pos, W1, g1, b1, rm1, rv1, W2, g2, b2, rm2, rv2,
        W3, g3, b3, rm3, rv3, cpos, nidx, out);
}

// Round 13
// 1382.952 us; speedup vs baseline: 2.2048x; 1.5922x over previous
//
#include <hip/hip_runtime.h>
#include <hip/hip_bf16.h>
#include <float.h>
#include <math.h>

#define BATCH 16
#define NPTS  4096
#define CIN   64
#define MCENT 1024
#define KNB   32
#define OUT_X (BATCH * MCENT * 128)

// ---- exact (non-contracted) f32 ops: bitwise-match numpy's separate roundings ----
__device__ __forceinline__ float f_sub(float a, float b){ float r; asm("v_sub_f32 %0, %1, %2" : "=v"(r) : "v"(a), "v"(b)); return r; }
__device__ __forceinline__ float f_mul(float a, float b){ float r; asm("v_mul_f32 %0, %1, %2" : "=v"(r) : "v"(a), "v"(b)); return r; }
__device__ __forceinline__ float f_add(float a, float b){ float r; asm("v_add_f32 %0, %1, %2" : "=v"(r) : "v"(a), "v"(b)); return r; }

__device__ __forceinline__ float dist2_exact(float px, float py, float pz,
                                             float lx, float ly, float lz) {
    float dx = f_sub(px, lx), dy = f_sub(py, ly), dz = f_sub(pz, lz);
    return f_add(f_add(f_mul(dx, dx), f_mul(dy, dy)), f_mul(dz, dz));
}

// DPP max step (bound_ctrl=false, full masks)
template <int CTRL>
__device__ __forceinline__ float dpp_max(float x) {
    int xi = __float_as_int(x);
    int yi = __builtin_amdgcn_update_dpp(xi, xi, CTRL, 0xF, 0xF, false);
    return fmaxf(x, __int_as_float(yi));
}
// max over each 32-lane half
__device__ __forceinline__ float half_max_f32(float v) {
    v = dpp_max<0xB1>(v);   // quad_perm xor1
    v = dpp_max<0x4E>(v);   // quad_perm xor2
    v = dpp_max<0x141>(v);  // row_half_mirror
    v = dpp_max<0x140>(v);  // row_mirror
    int s = __builtin_amdgcn_ds_swizzle(__float_as_int(v), 0x401F); // xor16
    return fmaxf(v, __int_as_float(s));
}
// full wave max
__device__ __forceinline__ float wave_max_f32(float v) {
    v = half_max_f32(v);
    float a = v, b = v;
    asm("v_permlane32_swap_b32 %0, %1" : "+v"(a), "+v"(b));  // xor32 (VALU)
    return fmaxf(a, b);
}

// ================= K1: farthest point sampling =================
// one block/batch; 512 threads; thread owns 8 contiguous points in registers.
// Winning lane of each wave writes (key, position) pre-barrier; post-barrier all
// threads read the 8 keys AND 8 positions in parallel, select winner via cndmask
// (no dependent sp[w] read, no shfl in the serial chain).
__global__ __launch_bounds__(512, 1) void fps_kernel(
    const float* __restrict__ pos, float* __restrict__ cpos)
{
    __shared__ __align__(16) float4 sp[NPTS];
    __shared__ __align__(16) unsigned long long swkey[2][8];
    __shared__ __align__(16) float4 swpos[2][8];
    __shared__ int widxarr[MCENT];

    const int b = blockIdx.x;
    const int t = threadIdx.x;
    const int lane = t & 63, wv = t >> 6;
    const float* pb = pos + (size_t)b * NPTS * 3;

    float px[8], py[8], pz[8], mind[8];
    {
        const float4* src = (const float4*)(pb + t * 24);
        float v[24];
#pragma unroll
        for (int q = 0; q < 6; ++q) {
            float4 f = src[q];
            v[q*4+0]=f.x; v[q*4+1]=f.y; v[q*4+2]=f.z; v[q*4+3]=f.w;
        }
#pragma unroll
        for (int jj = 0; jj < 8; ++jj) {
            int n = t * 8 + jj;
            px[jj]=v[jj*3+0]; py[jj]=v[jj*3+1]; pz[jj]=v[jj*3+2];
            sp[n] = make_float4(px[jj], py[jj], pz[jj], 0.f);
            mind[jj] = 1e10f;
        }
    }
    if (t == 0) widxarr[0] = 0;
    __syncthreads();

    float4 L = make_float4(pb[0], pb[1], pb[2], 0.f);   // centroid 0 = point 0
    for (int i = 1; i < MCENT; ++i) {
#pragma unroll
        for (int jj = 0; jj < 8; ++jj) {
            float d = dist2_exact(px[jj], py[jj], pz[jj], L.x, L.y, L.z);
            mind[jj] = fminf(mind[jj], d);
        }
        float tmax = fmaxf(fmaxf(fmaxf(mind[0],mind[1]), fmaxf(mind[2],mind[3])),
                           fmaxf(fmaxf(mind[4],mind[5]), fmaxf(mind[6],mind[7])));
        float wmax = wave_max_f32(tmax);
        int cand = 0; float wx = 0.f, wy = 0.f, wz = 0.f;
#pragma unroll
        for (int jj = 7; jj >= 0; --jj)
            if (mind[jj] == wmax) { cand = t * 8 + jj; wx = px[jj]; wy = py[jj]; wz = pz[jj]; }
        unsigned long long msk = __ballot(tmax == wmax);  // nonzero by construction
        int first = __ffsll(msk) - 1;        // smallest lane = smallest point index
        if (lane == first) {
            swkey[i & 1][wv] = ((unsigned long long)__float_as_uint(wmax) << 32)
                             | (unsigned)(NPTS - 1 - cand);
            swpos[i & 1][wv] = make_float4(wx, wy, wz, 0.f);
        }
        __syncthreads();                     // the only barrier per iteration
        // parallel reads of all keys+positions, then cndmask select
        unsigned long long kq[8]; float4 pq[8];
#pragma unroll
        for (int q = 0; q < 8; ++q) { kq[q] = swkey[i & 1][q]; pq[q] = swpos[i & 1][q]; }
        unsigned long long best = kq[0]; float4 bp = pq[0];
#pragma unroll
        for (int q = 1; q < 8; ++q)
            if (kq[q] > best) { best = kq[q]; bp = pq[q]; }
        L = bp;
        if (t == 0) widxarr[i] = (NPTS - 1) - (int)(unsigned)(best & 0xFFFFFFFFull);
    }
    __syncthreads();
#pragma unroll
    for (int e = 0; e < 2; ++e) {
        int c = t + e * 512;
        float4 P = sp[widxarr[c]];
        float* cp = cpos + ((size_t)b * MCENT + c) * 3;
        cp[0] = P.x; cp[1] = P.y; cp[2] = P.z;
    }
}

// ================= K2: ball query (unchanged) =================
__global__ __launch_bounds__(256) void ballq_kernel(
    const float* __restrict__ pos, const float* __restrict__ cpos,
    int* __restrict__ nidx)
{
    const int wid  = blockIdx.x * 4 + (threadIdx.x >> 6);
    const int lane = threadIdx.x & 63;
    const int b    = wid >> 10;
    const float* pb = pos + (size_t)b * NPTS * 3;
    const float cx = cpos[wid * 3 + 0];
    const float cy = cpos[wid * 3 + 1];
    const float cz = cpos[wid * 3 + 2];
    const float R2 = (float)(0.2 * 0.2);
    int* outp = nidx + (size_t)wid * KNB;

    int cnt = 0;
    for (int j0 = 0; j0 < NPTS; j0 += 64) {
        int j = j0 + lane;
        float x = pb[j * 3 + 0], y = pb[j * 3 + 1], z = pb[j * 3 + 2];
        float d = dist2_exact(x, y, z, cx, cy, cz);
        bool valid = (d <= R2);
        unsigned long long msk = __ballot(valid);
        if (valid) {
            int rank = cnt + __popcll(msk & ((1ull << lane) - 1ull));
            if (rank < KNB) outp[rank] = j;
        }
        cnt += __popcll(msk);
        if (cnt >= KNB) break;
    }
    int nv = cnt < KNB ? cnt : KNB;
    if (lane >= nv && lane < KNB) outp[lane] = -1;
}

// ================= K3: gather + shared MLP + DPP max-pool (LDS-row, small code) =================
// 256 threads = 8 centroids x 32 rows; one row per thread, row lives in LDS
// (stride 69: 5t+kk mod 32 -> 2-way conflict = free). kk-loops at unroll 2 keep
// code ~2KB (I$-friendly; full unroll was the round-9..12 killer) and let the
// compiler merge ds_reads + prefetch s_load weights. L1/L2 use acc[64]; L3 runs
// four 32-ch passes (a2[32]) folding BN+mask+DPP-pool+leader float4 stores.
__global__ __launch_bounds__(256, 1) void mlp_kernel(
    const float* __restrict__ x, const float* __restrict__ pos,
    const float* __restrict__ W1, const float* __restrict__ g1, const float* __restrict__ b1,
    const float* __restrict__ rm1, const float* __restrict__ rv1,
    const float* __restrict__ W2, const float* __restrict__ g2, const float* __restrict__ b2,
    const float* __restrict__ rm2, const float* __restrict__ rv2,
    const float* __restrict__ W3, const float* __restrict__ g3, const float* __restrict__ b3,
    const float* __restrict__ rm3, const float* __restrict__ rv3,
    const float* __restrict__ cpos, const int* __restrict__ nidx,
    float* __restrict__ out)
{
    __shared__ float hbuf[256 * 69];
    __shared__ __align__(16) float sscale[256];
    __shared__ __align__(16) float sbias[256];

    const int t   = threadIdx.x;
    const int g   = t >> 5;
    const int k   = t & 31;
    const int cid0 = blockIdx.x * 8;
    const int cid  = cid0 + g;
    const int b    = cid >> 10;

    {
        float gg, bb, rm, rv;
        if (t < 64)       { gg = g1[t];     bb = b1[t];     rm = rm1[t];     rv = rv1[t]; }
        else if (t < 128) { int c = t - 64;  gg = g2[c]; bb = b2[c]; rm = rm2[c]; rv = rv2[c]; }
        else              { int c = t - 128; gg = g3[c]; bb = b3[c]; rm = rm3[c]; rv = rv3[c]; }
        float s = gg / sqrtf(rv + 1e-5f);
        sscale[t] = s;
        sbias[t]  = bb - rm * s;
    }

    const int j = nidx[(size_t)cid * KNB + k];
    const bool valid = (j >= 0);
    float* hrow = &hbuf[t * 69];
    if (valid) {
        const float4* xr = (const float4*)(x + ((size_t)b * NPTS + j) * CIN);
#pragma unroll
        for (int q = 0; q < 16; ++q) {
            float4 v = xr[q];
            hrow[q*4+0]=v.x; hrow[q*4+1]=v.y; hrow[q*4+2]=v.z; hrow[q*4+3]=v.w;
        }
        const float* pr = pos + ((size_t)b * NPTS + j) * 3;
        hrow[64] = f_sub(pr[0], cpos[cid * 3 + 0]);
        hrow[65] = f_sub(pr[1], cpos[cid * 3 + 1]);
        hrow[66] = f_sub(pr[2], cpos[cid * 3 + 2]);
    } else {
        for (int q = 0; q < 67; ++q) hrow[q] = 0.f;
    }
    __syncthreads();   // sscale/sbias ready

    float acc[64];
    // ---- layer 1: 67 -> 64 ----
#pragma unroll
    for (int c = 0; c < 64; ++c) acc[c] = 0.f;
#pragma unroll 2
    for (int kk = 0; kk < 67; ++kk) {
        const float hv = hrow[kk];
        const float* wr = W1 + kk * 64;     // wave-uniform -> s_load
#pragma unroll
        for (int c = 0; c < 64; ++c) acc[c] = fmaf(hv, wr[c], acc[c]);
    }
#pragma unroll
    for (int c = 0; c < 64; ++c)
        hrow[c] = fmaxf(fmaf(acc[c], sscale[c], sbias[c]), 0.f);   // same-thread RAW, no barrier

    // ---- layer 2: 64 -> 64 ----
#pragma unroll
    for (int c = 0; c < 64; ++c) acc[c] = 0.f;
#pragma unroll 2
    for (int kk = 0; kk < 64; ++kk) {
        const float hv = hrow[kk];
        const float* wr = W2 + kk * 64;
#pragma unroll
        for (int c = 0; c < 64; ++c) acc[c] = fmaf(hv, wr[c], acc[c]);
    }
#pragma unroll
    for (int c = 0; c < 64; ++c)
        hrow[c] = fmaxf(fmaf(acc[c], sscale[64 + c], sbias[64 + c]), 0.f);

    // ---- layer 3: 64 -> 128 in four 32-ch passes; BN+mask+pool+store folded ----
#pragma unroll
    for (int p = 0; p < 4; ++p) {
        float a2[32];
#pragma unroll
        for (int c = 0; c < 32; ++c) a2[c] = 0.f;
#pragma unroll 2
        for (int kk = 0; kk < 64; ++kk) {
            const float hv = hrow[kk];
            const float* wr = W3 + kk * 128 + p * 32;
#pragma unroll
            for (int c = 0; c < 32; ++c) a2[c] = fmaf(hv, wr[c], a2[c]);
        }
#pragma unroll
        for (int c4 = 0; c4 < 8; ++c4) {
            float4 sc = *(const float4*)&sscale[128 + p * 32 + c4 * 4];
            float4 sb = *(const float4*)&sbias[128 + p * 32 + c4 * 4];
            float v0 = fmaxf(fmaf(a2[c4*4+0], sc.x, sb.x), 0.f);
            float v1 = fmaxf(fmaf(a2[c4*4+1], sc.y, sb.y), 0.f);
            float v2 = fmaxf(fmaf(a2[c4*4+2], sc.z, sb.z), 0.f);
            float v3 = fmaxf(fmaf(a2[c4*4+3], sc.w, sb.w), 0.f);
            if (!valid) { v0 = -FLT_MAX; v1 = -FLT_MAX; v2 = -FLT_MAX; v3 = -FLT_MAX; }
            a2[c4*4+0] = half_max_f32(v0);
            a2[c4*4+1] = half_max_f32(v1);
            a2[c4*4+2] = half_max_f32(v2);
            a2[c4*4+3] = half_max_f32(v3);
        }
        if (k == 0) {                        // lanes 0 and 32: group leaders
            float* op = out + (size_t)cid * 128 + p * 32;
#pragma unroll
            for (int c4 = 0; c4 < 8; ++c4) {
                *(float4*)(op + c4 * 4) =
                    make_float4(a2[c4*4+0], a2[c4*4+1], a2[c4*4+2], a2[c4*4+3]);
            }
        }
    }
}

extern "C" void kernel_launch(void* const* d_in, const int* in_sizes, int n_in,
                              void* d_out, int out_size, void* d_ws, size_t ws_size,
                              hipStream_t stream) {
    const float* x   = (const float*)d_in[0];
    const float* pos = (const float*)d_in[1];
    const float* W1  = (const float*)d_in[2];
    const float* g1  = (const float*)d_in[3];
    const float* b1  = (const float*)d_in[4];
    const float* rm1 = (const float*)d_in[5];
    const float* rv1 = (const float*)d_in[6];
    const float* W2  = (const float*)d_in[7];
    const float* g2  = (const float*)d_in[8];
    const float* b2  = (const float*)d_in[9];
    const float* rm2 = (const float*)d_in[10];
    const float* rv2 = (const float*)d_in[11];
    const float* W3  = (const float*)d_in[12];
    const float* g3  = (const float*)d_in[13];
    const float* b3  = (const float*)d_in[14];
    const float* rm3 = (const float*)d_in[15];
    const float* rv3 = (const float*)d_in[16];

    float* out  = (float*)d_out;
    float* cpos = out + OUT_X;          // second output region
    int*   nidx = (int*)d_ws;           // B*M*K ints = 2 MiB scratch

    fps_kernel<<<dim3(BATCH), dim3(512), 0, stream>>>(pos, cpos);
    ballq_kernel<<<dim3(BATCH * MCENT / 4), dim3(256), 0, stream>>>(pos, cpos, nidx);
    mlp_kernel<<<dim3(BATCH * MCENT / 8), dim3(256), 0, stream>>>(
        x, pos, W1, g1, b1, rm1, rv1, W2, g2, b2, rm2, rv2,
        W3, g3, b3, rm3, rv3, cpos, nidx, out);
}

// Round 14
// 1148.334 us; speedup vs baseline: 2.6553x; 1.2043x over previous
//
#include <hip/hip_runtime.h>
#include <hip/hip_bf16.h>
#include <float.h>
#include <math.h>

#define BATCH 16
#define NPTS  4096
#define CIN   64
#define MCENT 1024
#define KNB   32
#define OUT_X (BATCH * MCENT * 128)

// ---- exact (non-contracted) f32 ops: bitwise-match numpy's separate roundings ----
__device__ __forceinline__ float f_sub(float a, float b){ float r; asm("v_sub_f32 %0, %1, %2" : "=v"(r) : "v"(a), "v"(b)); return r; }
__device__ __forceinline__ float f_mul(float a, float b){ float r; asm("v_mul_f32 %0, %1, %2" : "=v"(r) : "v"(a), "v"(b)); return r; }
__device__ __forceinline__ float f_add(float a, float b){ float r; asm("v_add_f32 %0, %1, %2" : "=v"(r) : "v"(a), "v"(b)); return r; }

__device__ __forceinline__ float dist2_exact(float px, float py, float pz,
                                             float lx, float ly, float lz) {
    float dx = f_sub(px, lx), dy = f_sub(py, ly), dz = f_sub(pz, lz);
    return f_add(f_add(f_mul(dx, dx), f_mul(dy, dy)), f_mul(dz, dz));
}

// DPP max step (bound_ctrl=false, full masks)
template <int CTRL>
__device__ __forceinline__ float dpp_max(float x) {
    int xi = __float_as_int(x);
    int yi = __builtin_amdgcn_update_dpp(xi, xi, CTRL, 0xF, 0xF, false);
    return fmaxf(x, __int_as_float(yi));
}
// max over each 32-lane half
__device__ __forceinline__ float half_max_f32(float v) {
    v = dpp_max<0xB1>(v);   // quad_perm xor1
    v = dpp_max<0x4E>(v);   // quad_perm xor2
    v = dpp_max<0x141>(v);  // row_half_mirror
    v = dpp_max<0x140>(v);  // row_mirror
    int s = __builtin_amdgcn_ds_swizzle(__float_as_int(v), 0x401F); // xor16
    return fmaxf(v, __int_as_float(s));
}
// full wave max
__device__ __forceinline__ float wave_max_f32(float v) {
    v = half_max_f32(v);
    float a = v, b = v;
    asm("v_permlane32_swap_b32 %0, %1" : "+v"(a), "+v"(b));  // xor32 (VALU)
    return fmaxf(a, b);
}

__device__ __forceinline__ unsigned long long umax64(unsigned long long a, unsigned long long b) {
    return a > b ? a : b;
}

// ================= K1: farthest point sampling (round-9 structure + tree-max scan) ========
// one block/batch; 512 threads; thread owns 8 contiguous points in registers.
// Per iteration: in-wave argmax (DPP + ballot/shfl), lane0 writes packed u64 key,
// ONE barrier, tree-max over the 8 keys -> winner index -> one sp[w] b128 read.
__global__ __launch_bounds__(512, 1) void fps_kernel(
    const float* __restrict__ pos, float* __restrict__ cpos)
{
    __shared__ __align__(16) float4 sp[NPTS];
    __shared__ __align__(16) unsigned long long swkey[2][8];
    __shared__ int widxarr[MCENT];

    const int b = blockIdx.x;
    const int t = threadIdx.x;
    const int lane = t & 63, wv = t >> 6;
    const float* pb = pos + (size_t)b * NPTS * 3;

    float px[8], py[8], pz[8], mind[8];
    {
        const float4* src = (const float4*)(pb + t * 24);
        float v[24];
#pragma unroll
        for (int q = 0; q < 6; ++q) {
            float4 f = src[q];
            v[q*4+0]=f.x; v[q*4+1]=f.y; v[q*4+2]=f.z; v[q*4+3]=f.w;
        }
#pragma unroll
        for (int jj = 0; jj < 8; ++jj) {
            int n = t * 8 + jj;
            px[jj]=v[jj*3+0]; py[jj]=v[jj*3+1]; pz[jj]=v[jj*3+2];
            sp[n] = make_float4(px[jj], py[jj], pz[jj], 0.f);
            mind[jj] = 1e10f;
        }
    }
    if (t == 0) widxarr[0] = 0;
    __syncthreads();

    int w = 0;
    for (int i = 1; i < MCENT; ++i) {
        float4 L = sp[w];                       // broadcast b128
#pragma unroll
        for (int jj = 0; jj < 8; ++jj) {
            float d = dist2_exact(px[jj], py[jj], pz[jj], L.x, L.y, L.z);
            mind[jj] = fminf(mind[jj], d);
        }
        float tmax = fmaxf(fmaxf(fmaxf(mind[0],mind[1]), fmaxf(mind[2],mind[3])),
                           fmaxf(fmaxf(mind[4],mind[5]), fmaxf(mind[6],mind[7])));
        float wmax = wave_max_f32(tmax);
        int cand = 0;
#pragma unroll
        for (int jj = 7; jj >= 0; --jj)
            if (mind[jj] == wmax) cand = t * 8 + jj;      // smallest matching j wins
        unsigned long long msk = __ballot(tmax == wmax);  // nonzero by construction
        int first = __ffsll(msk) - 1;                     // smallest lane = smallest index
        int candw = __shfl(cand, first);
        if (lane == 0)
            swkey[i & 1][wv] = ((unsigned long long)__float_as_uint(wmax) << 32)
                             | (unsigned)(NPTS - 1 - candw);
        __syncthreads();                        // the only barrier per iteration
        // depth-3 tree max over 8 keys (larger dist wins; tie -> smaller index)
        const unsigned long long* kb = swkey[i & 1];
        unsigned long long m01 = umax64(kb[0], kb[1]);
        unsigned long long m23 = umax64(kb[2], kb[3]);
        unsigned long long m45 = umax64(kb[4], kb[5]);
        unsigned long long m67 = umax64(kb[6], kb[7]);
        unsigned long long best = umax64(umax64(m01, m23), umax64(m45, m67));
        w = (NPTS - 1) - (int)(unsigned)(best & 0xFFFFFFFFull);
        if (t == 0) widxarr[i] = w;
    }
    __syncthreads();
#pragma unroll
    for (int e = 0; e < 2; ++e) {
        int c = t + e * 512;
        float4 P = sp[widxarr[c]];
        float* cp = cpos + ((size_t)b * MCENT + c) * 3;
        cp[0] = P.x; cp[1] = P.y; cp[2] = P.z;
    }
}

// ================= K2: ball query (unchanged) =================
__global__ __launch_bounds__(256) void ballq_kernel(
    const float* __restrict__ pos, const float* __restrict__ cpos,
    int* __restrict__ nidx)
{
    const int wid  = blockIdx.x * 4 + (threadIdx.x >> 6);
    const int lane = threadIdx.x & 63;
    const int b    = wid >> 10;
    const float* pb = pos + (size_t)b * NPTS * 3;
    const float cx = cpos[wid * 3 + 0];
    const float cy = cpos[wid * 3 + 1];
    const float cz = cpos[wid * 3 + 2];
    const float R2 = (float)(0.2 * 0.2);
    int* outp = nidx + (size_t)wid * KNB;

    int cnt = 0;
    for (int j0 = 0; j0 < NPTS; j0 += 64) {
        int j = j0 + lane;
        float x = pb[j * 3 + 0], y = pb[j * 3 + 1], z = pb[j * 3 + 2];
        float d = dist2_exact(x, y, z, cx, cy, cz);
        bool valid = (d <= R2);
        unsigned long long msk = __ballot(valid);
        if (valid) {
            int rank = cnt + __popcll(msk & ((1ull << lane) - 1ull));
            if (rank < KNB) outp[rank] = j;
        }
        cnt += __popcll(msk);
        if (cnt >= KNB) break;
    }
    int nv = cnt < KNB ? cnt : KNB;
    if (lane >= nv && lane < KNB) outp[lane] = -1;
}

// ================= K3: gather + shared MLP + DPP max-pool (round-13, unchanged) ==========
// 256 threads = 8 centroids x 32 rows; one row per thread, row lives in LDS.
// kk-loops at unroll 2 keep code ~2KB (I$-friendly); L1/L2 use acc[64]; L3 runs
// four 32-ch passes (a2[32]) folding BN+mask+DPP-pool+leader float4 stores.
__global__ __launch_bounds__(256, 1) void mlp_kernel(
    const float* __restrict__ x, const float* __restrict__ pos,
    const float* __restrict__ W1, const float* __restrict__ g1, const float* __restrict__ b1,
    const float* __restrict__ rm1, const float* __restrict__ rv1,
    const float* __restrict__ W2, const float* __restrict__ g2, const float* __restrict__ b2,
    const float* __restrict__ rm2, const float* __restrict__ rv2,
    const float* __restrict__ W3, const float* __restrict__ g3, const float* __restrict__ b3,
    const float* __restrict__ rm3, const float* __restrict__ rv3,
    const float* __restrict__ cpos, const int* __restrict__ nidx,
    float* __restrict__ out)
{
    __shared__ float hbuf[256 * 69];
    __shared__ __align__(16) float sscale[256];
    __shared__ __align__(16) float sbias[256];

    const int t   = threadIdx.x;
    const int g   = t >> 5;
    const int k   = t & 31;
    const int cid0 = blockIdx.x * 8;
    const int cid  = cid0 + g;
    const int b    = cid >> 10;

    {
        float gg, bb, rm, rv;
        if (t < 64)       { gg = g1[t];     bb = b1[t];     rm = rm1[t];     rv = rv1[t]; }
        else if (t < 128) { int c = t - 64;  gg = g2[c]; bb = b2[c]; rm = rm2[c]; rv = rv2[c]; }
        else              { int c = t - 128; gg = g3[c]; bb = b3[c]; rm = rm3[c]; rv = rv3[c]; }
        float s = gg / sqrtf(rv + 1e-5f);
        sscale[t] = s;
        sbias[t]  = bb - rm * s;
    }

    const int j = nidx[(size_t)cid * KNB + k];
    const bool valid = (j >= 0);
    float* hrow = &hbuf[t * 69];
    if (valid) {
        const float4* xr = (const float4*)(x + ((size_t)b * NPTS + j) * CIN);
#pragma unroll
        for (int q = 0; q < 16; ++q) {
            float4 v = xr[q];
            hrow[q*4+0]=v.x; hrow[q*4+1]=v.y; hrow[q*4+2]=v.z; hrow[q*4+3]=v.w;
        }
        const float* pr = pos + ((size_t)b * NPTS + j) * 3;
        hrow[64] = f_sub(pr[0], cpos[cid * 3 + 0]);
        hrow[65] = f_sub(pr[1], cpos[cid * 3 + 1]);
        hrow[66] = f_sub(pr[2], cpos[cid * 3 + 2]);
    } else {
        for (int q = 0; q < 67; ++q) hrow[q] = 0.f;
    }
    __syncthreads();   // sscale/sbias ready

    float acc[64];
    // ---- layer 1: 67 -> 64 ----
#pragma unroll
    for (int c = 0; c < 64; ++c) acc[c] = 0.f;
#pragma unroll 2
    for (int kk = 0; kk < 67; ++kk) {
        const float hv = hrow[kk];
        const float* wr = W1 + kk * 64;     // wave-uniform -> s_load
#pragma unroll
        for (int c = 0; c < 64; ++c) acc[c] = fmaf(hv, wr[c], acc[c]);
    }
#pragma unroll
    for (int c = 0; c < 64; ++c)
        hrow[c] = fmaxf(fmaf(acc[c], sscale[c], sbias[c]), 0.f);   // same-thread RAW

    // ---- layer 2: 64 -> 64 ----
#pragma unroll
    for (int c = 0; c < 64; ++c) acc[c] = 0.f;
#pragma unroll 2
    for (int kk = 0; kk < 64; ++kk) {
        const float hv = hrow[kk];
        const float* wr = W2 + kk * 64;
#pragma unroll
        for (int c = 0; c < 64; ++c) acc[c] = fmaf(hv, wr[c], acc[c]);
    }
#pragma unroll
    for (int c = 0; c < 64; ++c)
        hrow[c] = fmaxf(fmaf(acc[c], sscale[64 + c], sbias[64 + c]), 0.f);

    // ---- layer 3: 64 -> 128 in four 32-ch passes; BN+mask+pool+store folded ----
#pragma unroll
    for (int p = 0; p < 4; ++p) {
        float a2[32];
#pragma unroll
        for (int c = 0; c < 32; ++c) a2[c] = 0.f;
#pragma unroll 2
        for (int kk = 0; kk < 64; ++kk) {
            const float hv = hrow[kk];
            const float* wr = W3 + kk * 128 + p * 32;
#pragma unroll
            for (int c = 0; c < 32; ++c) a2[c] = fmaf(hv, wr[c], a2[c]);
        }
#pragma unroll
        for (int c4 = 0; c4 < 8; ++c4) {
            float4 sc = *(const float4*)&sscale[128 + p * 32 + c4 * 4];
            float4 sb = *(const float4*)&sbias[128 + p * 32 + c4 * 4];
            float v0 = fmaxf(fmaf(a2[c4*4+0], sc.x, sb.x), 0.f);
            float v1 = fmaxf(fmaf(a2[c4*4+1], sc.y, sb.y), 0.f);
            float v2 = fmaxf(fmaf(a2[c4*4+2], sc.z, sb.z), 0.f);
            float v3 = fmaxf(fmaf(a2[c4*4+3], sc.w, sb.w), 0.f);
            if (!valid) { v0 = -FLT_MAX; v1 = -FLT_MAX; v2 = -FLT_MAX; v3 = -FLT_MAX; }
            a2[c4*4+0] = half_max_f32(v0);
            a2[c4*4+1] = half_max_f32(v1);
            a2[c4*4+2] = half_max_f32(v2);
            a2[c4*4+3] = half_max_f32(v3);
        }
        if (k == 0) {                        // lanes 0 and 32: group leaders
            float* op = out + (size_t)cid * 128 + p * 32;
#pragma unroll
            for (int c4 = 0; c4 < 8; ++c4) {
                *(float4*)(op + c4 * 4) =
                    make_float4(a2[c4*4+0], a2[c4*4+1], a2[c4*4+2], a2[c4*4+3]);
            }
        }
    }
}

extern "C" void kernel_launch(void* const* d_in, const int* in_sizes, int n_in,
                              void* d_out, int out_size, void* d_ws, size_t ws_size,
                              hipStream_t stream) {
    const float* x   = (const float*)d_in[0];
    const float* pos = (const float*)d_in[1];
    const float* W1  = (const float*)d_in[2];
    const float* g1  = (const float*)d_in[3];
    const float* b1  = (const float*)d_in[4];
    const float* rm1 = (const float*)d_in[5];
    const float* rv1 = (const float*)d_in[6];
    const float* W2  = (const float*)d_in[7];
    const float* g2  = (const float*)d_in[8];
    const float* b2  = (const float*)d_in[9];
    const float* rm2 = (const float*)d_in[10];
    const float* rv2 = (const float*)d_in[11];
    const float* W3  = (const float*)d_in[12];
    const float* g3  = (const float*)d_in[13];
    const float* b3  = (const float*)d_in[14];
    const float* rm3 = (const float*)d_in[15];
    const float* rv3 = (const float*)d_in[16];

    float* out  = (float*)d_out;
    float* cpos = out + OUT_X;          // second output region
    int*   nidx = (int*)d_ws;           // B*M*K ints = 2 MiB scratch

    fps_kernel<<<dim3(BATCH), dim3(512), 0, stream>>>(pos, cpos);
    ballq_kernel<<<dim3(BATCH * MCENT / 4), dim3(256), 0, stream>>>(pos, cpos, nidx);
    mlp_kernel<<<dim3(BATCH * MCENT / 8), dim3(256), 0, stream>>>(
        x, pos, W1, g1, b1, rm1, rv1, W2, g2, b2, rm2, rv2,
        W3, g3, b3, rm3, rv3, cpos, nidx, out);
}